// Round 20
// baseline (38.376 us; speedup 1.0000x reference)
//
#include <hip/hip_runtime.h>
#include <math.h>

// Problem dims (fixed by setup_inputs)
constexpr int B = 8;
constexpr int A = 49104;
constexpr int C = 80;       // classes
constexpr int M = 32;       // max annotations
constexpr int TILE = 256;   // anchors per block == threads per block
constexpr int NTILES = (A + TILE - 1) / TILE;  // 192

#define SBAR() __builtin_amdgcn_sched_barrier(0)

// ws layout: slots [(b*NTILES+tile)*4 + {0,1,2}] = per-block {cls(log2), reg, npos}
// (PLAIN STORES, unconditionally written every call -> no init, no atomics).

__device__ __forceinline__ void focal_quad(const float4 p4, const float wq,
                                           float& accA, float& accB) {
    const float px = fminf(fmaxf(p4.x, 1e-4f), 1.0f - 1e-4f);
    const float py = fminf(fmaxf(p4.y, 1e-4f), 1.0f - 1e-4f);
    const float pz = fminf(fmaxf(p4.z, 1e-4f), 1.0f - 1e-4f);
    const float pw = fminf(fmaxf(p4.w, 1e-4f), 1.0f - 1e-4f);
    accA = fmaf(-wq, px * px * __log2f(1.0f - px), accA);
    accB = fmaf(-wq, py * py * __log2f(1.0f - py), accB);
    accA = fmaf(-wq, pz * pz * __log2f(1.0f - pz), accA);
    accB = fmaf(-wq, pw * pw * __log2f(1.0f - pw), accB);
}

// R19 kernel + entry prefetch of Phase-B's first 5 quads (always in-bounds:
// nquad >= 4160 > t+4*TILE max 1279). Under the old atomic floor this lever
// was masked (R9/R11/R12); retesting it clean.
__global__ __launch_bounds__(TILE, 8) void focal_main_kernel(
    const float* __restrict__ cls,      // (B, A, C)
    const float* __restrict__ reg,      // (B, A, 4)
    const float* __restrict__ anchors,  // (A, 4)  y1,x1,y2,x2
    const float* __restrict__ ann,      // (B, M, 5) x1,y1,x2,y2,label
    float* __restrict__ ws)
{
    __shared__ float s_ann[M][5];
    __shared__ float s_w[TILE];       // 0.75 for pos|neg anchors, 0 for ignore/tail
    __shared__ float s_red[3][4];

    const int t    = threadIdx.x;
    const int tile = blockIdx.x;
    const int b    = blockIdx.y;
    const int base = tile * TILE;
    const int nA   = min(TILE, A - base);

    // --- Prefetch Phase-B batch 0 at kernel entry (unconditional, no branch
    // for MachineSink to cross); SBAR pins the issue point. Latency hides
    // under annotation staging + Phase A (~600 cyc).
    const float4* cp = (const float4*)(cls + ((size_t)b * A + base) * C);
    const float4 q0 = cp[t];
    const float4 q1 = cp[t +     TILE];
    const float4 q2 = cp[t + 2 * TILE];
    const float4 q3 = cp[t + 3 * TILE];
    const float4 q4 = cp[t + 4 * TILE];
    SBAR();

    if (t < M * 5) ((float*)s_ann)[t] = ann[b * M * 5 + t];
    __syncthreads();

    float cls_part  = 0.0f;   // log2 units
    float reg_part  = 0.0f;
    float npos_part = 0.0f;
    float w = 0.0f;

    if (t < nA) {
        const int a = base + t;
        const float4 an = ((const float4*)anchors)[a];  // y1,x1,y2,x2
        const float aw  = an.w - an.y;
        const float ah  = an.z - an.x;
        const float acx = an.y + 0.5f * aw;
        const float acy = an.x + 0.5f * ah;
        const float aarea = ah * aw;

        float best = -2.0f;   // below the -1 sentinel
        int   arg  = 0;
        #pragma unroll
        for (int j = 0; j < M; ++j) {
            const float bx1 = s_ann[j][0];
            const float by1 = s_ann[j][1];
            const float bx2 = s_ann[j][2];
            const float by2 = s_ann[j][3];
            const float lb  = s_ann[j][4];
            float iw = fminf(an.w, bx2) - fmaxf(an.y, bx1);
            float ih = fminf(an.z, by2) - fmaxf(an.x, by1);
            iw = fmaxf(iw, 0.0f);
            ih = fmaxf(ih, 0.0f);
            const float inter = iw * ih;
            const float area  = (bx2 - bx1) * (by2 - by1);
            const float ua    = fmaxf(aarea + area - inter, 1e-8f);
            const float iou   = (lb != -1.0f) ? (inter / ua) : -1.0f;
            if (iou > best) { best = iou; arg = j; }   // strict > == argmax first-occurrence
        }
        const bool pos = best >= 0.5f;
        const bool neg = best <  0.4f;
        w = (pos || neg) ? 0.75f : 0.0f;

        if (pos) {
            npos_part = 1.0f;
            const int lab = (int)s_ann[arg][4];
            // cls correction for the label element (then-term minus the
            // else-term Phase B will blindly add). All in log2 units.
            const float pl = fminf(fmaxf(cls[((size_t)b * A + a) * C + lab], 1e-4f), 1.0f - 1e-4f);
            const float ql = 1.0f - pl;
            cls_part = -0.25f * ql * ql * __log2f(pl) + 0.75f * pl * pl * __log2f(ql);

            // smooth-L1 regression term (natural-log units)
            const float4 r = ((const float4*)reg)[(size_t)b * A + a];
            const float ax1 = s_ann[arg][0];
            const float ay1 = s_ann[arg][1];
            const float ax2 = s_ann[arg][2];
            const float ay2 = s_ann[arg][3];
            float gw = ax2 - ax1;
            float gh = ay2 - ay1;
            const float gcx = ax1 + 0.5f * gw;
            const float gcy = ay1 + 0.5f * gh;
            gw = fmaxf(gw, 1.0f);
            gh = fmaxf(gh, 1.0f);
            const float t0 = (gcy - acy) / ah;
            const float t1 = (gcx - acx) / aw;
            const float t2 = __logf(gh / ah);
            const float t3 = __logf(gw / aw);
            const float d0 = fabsf(t0 - r.x);
            const float d1 = fabsf(t1 - r.y);
            const float d2 = fabsf(t2 - r.z);
            const float d3 = fabsf(t3 - r.w);
            const float TH = 1.0f / 9.0f;
            const float SH = 0.5f / 9.0f;
            reg_part = ((d0 <= TH) ? 4.5f * d0 * d0 : d0 - SH)
                     + ((d1 <= TH) ? 4.5f * d1 * d1 : d1 - SH)
                     + ((d2 <= TH) ? 4.5f * d2 * d2 : d2 - SH)
                     + ((d3 <= TH) ? 4.5f * d3 * d3 : d3 - SH);
        }
    }
    s_w[t] = w;
    __syncthreads();

    // Phase B: consume prefetched batch 0, then the 5-deep batched stream.
    const int nquad = nA * (C / 4);   // 20 float4 per anchor; >= 4160 always
    float accA = cls_part, accB = 0.0f;
    {
        const float w0 = s_w[(unsigned)(t)            / 20u];
        const float w1 = s_w[(unsigned)(t +     TILE) / 20u];
        const float w2 = s_w[(unsigned)(t + 2 * TILE) / 20u];
        const float w3 = s_w[(unsigned)(t + 3 * TILE) / 20u];
        const float w4 = s_w[(unsigned)(t + 4 * TILE) / 20u];
        focal_quad(q0, w0, accA, accB);
        focal_quad(q1, w1, accA, accB);
        focal_quad(q2, w2, accA, accB);
        focal_quad(q3, w3, accA, accB);
        focal_quad(q4, w4, accA, accB);
    }

    int k = t + 5 * TILE;
    for (; k + 4 * TILE < nquad; k += 5 * TILE) {
        const float4 p0 = cp[k];
        const float4 p1 = cp[k +     TILE];
        const float4 p2 = cp[k + 2 * TILE];
        const float4 p3 = cp[k + 3 * TILE];
        const float4 p4 = cp[k + 4 * TILE];
        const float w0 = s_w[(unsigned)(k)            / 20u];
        const float w1 = s_w[(unsigned)(k +     TILE) / 20u];
        const float w2 = s_w[(unsigned)(k + 2 * TILE) / 20u];
        const float w3 = s_w[(unsigned)(k + 3 * TILE) / 20u];
        const float w4 = s_w[(unsigned)(k + 4 * TILE) / 20u];
        focal_quad(p0, w0, accA, accB);
        focal_quad(p1, w1, accA, accB);
        focal_quad(p2, w2, accA, accB);
        focal_quad(p3, w3, accA, accB);
        focal_quad(p4, w4, accA, accB);
    }
    for (; k < nquad; k += TILE) {
        const float4 q = cp[k];
        const float wq = s_w[(unsigned)k / 20u];
        focal_quad(q, wq, accA, accB);
    }
    cls_part = accA + accB;

    // Block reduction: wave shuffle then cross-wave via LDS.
    for (int off = 32; off > 0; off >>= 1) {
        cls_part  += __shfl_down(cls_part,  off, 64);
        reg_part  += __shfl_down(reg_part,  off, 64);
        npos_part += __shfl_down(npos_part, off, 64);
    }
    const int wave = t >> 6;
    const int lane = t & 63;
    if (lane == 0) {
        s_red[0][wave] = cls_part;
        s_red[1][wave] = reg_part;
        s_red[2][wave] = npos_part;
    }
    __syncthreads();
    if (t == 0) {
        float cs = 0.0f, rs = 0.0f, ns = 0.0f;
        #pragma unroll
        for (int wv = 0; wv < 4; ++wv) {
            cs += s_red[0][wv];
            rs += s_red[1][wv];
            ns += s_red[2][wv];
        }
        // CONTENTION-FREE: plain stores to this block's private slot.
        float* slot = ws + ((size_t)(b * NTILES + tile) << 2);
        slot[0] = cs;
        slot[1] = rs;
        slot[2] = ns;
    }
}

// Merged reduce+finalize: one block, 8 waves; wave w reduces image w's 192
// slots (3 slots/lane), then thread 0 combines the 8 images.
__global__ __launch_bounds__(512) void tail_kernel(
    const float* __restrict__ ws_in,
    const float* __restrict__ ann,
    float* __restrict__ out)
{
    const int t    = threadIdx.x;
    const int b    = t >> 6;        // wave index == image
    const int lane = t & 63;

    float c = 0.0f, r = 0.0f, n = 0.0f;
    #pragma unroll
    for (int s = 0; s < 3; ++s) {
        const int tile = lane * 3 + s;   // 64*3 = 192 slots
        const float* slot = ws_in + ((size_t)(b * NTILES + tile) << 2);
        c += slot[0];
        r += slot[1];
        n += slot[2];
    }
    for (int off = 32; off > 0; off >>= 1) {
        c += __shfl_down(c, off, 64);
        r += __shfl_down(r, off, 64);
        n += __shfl_down(n, off, 64);
    }

    __shared__ float s_cls[B], s_reg[B];
    if (lane == 0) {
        bool has_valid = false;
        for (int m = 0; m < M; ++m)
            has_valid = has_valid || (ann[b * M * 5 + m * 5 + 4] != -1.0f);
        // cls accumulator is in log2 units -> scale by ln(2)
        const float cs = 0.69314718056f * c / fmaxf(n, 1.0f);
        s_cls[b] = has_valid ? cs : 0.0f;
        s_reg[b] = (n > 0.0f) ? (r / fmaxf(n * 4.0f, 1.0f)) : 0.0f;
    }
    __syncthreads();
    if (t == 0) {
        float cv = 0.0f, rv = 0.0f;
        #pragma unroll
        for (int i = 0; i < B; ++i) { cv += s_cls[i]; rv += s_reg[i]; }
        out[0] = cv * (1.0f / (float)B);
        out[1] = rv * (1.0f / (float)B);
    }
}

extern "C" void kernel_launch(void* const* d_in, const int* in_sizes, int n_in,
                              void* d_out, int out_size, void* d_ws, size_t ws_size,
                              hipStream_t stream) {
    const float* cls     = (const float*)d_in[0];
    const float* reg     = (const float*)d_in[1];
    const float* anchors = (const float*)d_in[2];
    const float* ann     = (const float*)d_in[3];
    float* out = (float*)d_out;
    float* ws  = (float*)d_ws;

    // No init kernel: every ws slot used is unconditionally overwritten
    // (plain stores), so the 0xAA poison never survives into a read.
    focal_main_kernel<<<dim3(NTILES, B), TILE, 0, stream>>>(cls, reg, anchors, ann, ws);
    tail_kernel<<<1, 512, 0, stream>>>(ws, ann, out);
}

// Round 21
// 30.591 us; speedup vs baseline: 1.2545x; 1.2545x over previous
//
#include <hip/hip_runtime.h>
#include <math.h>

// Problem dims (fixed by setup_inputs)
constexpr int B = 8;
constexpr int A = 49104;
constexpr int C = 80;       // classes
constexpr int M = 32;       // max annotations
constexpr int TILE = 256;   // anchors per block == threads per block
constexpr int NTILES = (A + TILE - 1) / TILE;  // 192

// ws layout: slots [(b*NTILES+tile)*4 + {0,1,2}] = per-block {cls(log2), reg, npos}
// (PLAIN STORES, unconditionally written every call -> no init, no atomics).

__device__ __forceinline__ void focal_quad(const float4 p4, const float wq,
                                           float& accA, float& accB) {
    const float px = fminf(fmaxf(p4.x, 1e-4f), 1.0f - 1e-4f);
    const float py = fminf(fmaxf(p4.y, 1e-4f), 1.0f - 1e-4f);
    const float pz = fminf(fmaxf(p4.z, 1e-4f), 1.0f - 1e-4f);
    const float pw = fminf(fmaxf(p4.w, 1e-4f), 1.0f - 1e-4f);
    accA = fmaf(-wq, px * px * __log2f(1.0f - px), accA);
    accB = fmaf(-wq, py * py * __log2f(1.0f - py), accB);
    accA = fmaf(-wq, pz * pz * __log2f(1.0f - pz), accA);
    accB = fmaf(-wq, pw * pw * __log2f(1.0f - pw), accB);
}

// R19-verified main kernel (30.5 us total, absmax 0.0) — reverted to after
// R20's entry-prefetch regression (38.4 us: 20 live batch VGPRs across
// Phase A + load contention with annotation staging).
__global__ __launch_bounds__(TILE, 8) void focal_main_kernel(
    const float* __restrict__ cls,      // (B, A, C)
    const float* __restrict__ reg,      // (B, A, 4)
    const float* __restrict__ anchors,  // (A, 4)  y1,x1,y2,x2
    const float* __restrict__ ann,      // (B, M, 5) x1,y1,x2,y2,label
    float* __restrict__ ws)
{
    __shared__ float s_ann[M][5];
    __shared__ float s_w[TILE];       // 0.75 for pos|neg anchors, 0 for ignore/tail
    __shared__ float s_red[3][4];

    const int t    = threadIdx.x;
    const int tile = blockIdx.x;
    const int b    = blockIdx.y;
    const int base = tile * TILE;
    const int nA   = min(TILE, A - base);

    if (t < M * 5) ((float*)s_ann)[t] = ann[b * M * 5 + t];
    __syncthreads();

    float cls_part  = 0.0f;   // log2 units
    float reg_part  = 0.0f;
    float npos_part = 0.0f;
    float w = 0.0f;

    if (t < nA) {
        const int a = base + t;
        const float4 an = ((const float4*)anchors)[a];  // y1,x1,y2,x2
        const float aw  = an.w - an.y;
        const float ah  = an.z - an.x;
        const float acx = an.y + 0.5f * aw;
        const float acy = an.x + 0.5f * ah;
        const float aarea = ah * aw;

        float best = -2.0f;   // below the -1 sentinel
        int   arg  = 0;
        #pragma unroll
        for (int j = 0; j < M; ++j) {
            const float bx1 = s_ann[j][0];
            const float by1 = s_ann[j][1];
            const float bx2 = s_ann[j][2];
            const float by2 = s_ann[j][3];
            const float lb  = s_ann[j][4];
            float iw = fminf(an.w, bx2) - fmaxf(an.y, bx1);
            float ih = fminf(an.z, by2) - fmaxf(an.x, by1);
            iw = fmaxf(iw, 0.0f);
            ih = fmaxf(ih, 0.0f);
            const float inter = iw * ih;
            const float area  = (bx2 - bx1) * (by2 - by1);
            const float ua    = fmaxf(aarea + area - inter, 1e-8f);
            const float iou   = (lb != -1.0f) ? (inter / ua) : -1.0f;
            if (iou > best) { best = iou; arg = j; }   // strict > == argmax first-occurrence
        }
        const bool pos = best >= 0.5f;
        const bool neg = best <  0.4f;
        w = (pos || neg) ? 0.75f : 0.0f;

        if (pos) {
            npos_part = 1.0f;
            const int lab = (int)s_ann[arg][4];
            // cls correction for the label element (then-term minus the
            // else-term Phase B will blindly add). All in log2 units.
            const float pl = fminf(fmaxf(cls[((size_t)b * A + a) * C + lab], 1e-4f), 1.0f - 1e-4f);
            const float ql = 1.0f - pl;
            cls_part = -0.25f * ql * ql * __log2f(pl) + 0.75f * pl * pl * __log2f(ql);

            // smooth-L1 regression term (natural-log units)
            const float4 r = ((const float4*)reg)[(size_t)b * A + a];
            const float ax1 = s_ann[arg][0];
            const float ay1 = s_ann[arg][1];
            const float ax2 = s_ann[arg][2];
            const float ay2 = s_ann[arg][3];
            float gw = ax2 - ax1;
            float gh = ay2 - ay1;
            const float gcx = ax1 + 0.5f * gw;
            const float gcy = ay1 + 0.5f * gh;
            gw = fmaxf(gw, 1.0f);
            gh = fmaxf(gh, 1.0f);
            const float t0 = (gcy - acy) / ah;
            const float t1 = (gcx - acx) / aw;
            const float t2 = __logf(gh / ah);
            const float t3 = __logf(gw / aw);
            const float d0 = fabsf(t0 - r.x);
            const float d1 = fabsf(t1 - r.y);
            const float d2 = fabsf(t2 - r.z);
            const float d3 = fabsf(t3 - r.w);
            const float TH = 1.0f / 9.0f;
            const float SH = 0.5f / 9.0f;
            reg_part = ((d0 <= TH) ? 4.5f * d0 * d0 : d0 - SH)
                     + ((d1 <= TH) ? 4.5f * d1 * d1 : d1 - SH)
                     + ((d2 <= TH) ? 4.5f * d2 * d2 : d2 - SH)
                     + ((d3 <= TH) ? 4.5f * d3 * d3 : d3 - SH);
        }
    }
    s_w[t] = w;
    __syncthreads();

    // Phase B: branchless focal-BCE "else-branch" stream, batched 5 deep.
    const float4* cp = (const float4*)(cls + ((size_t)b * A + base) * C);
    const int nquad = nA * (C / 4);   // 20 float4 per anchor
    float accA = cls_part, accB = 0.0f;

    int k = t;
    for (; k + 4 * TILE < nquad; k += 5 * TILE) {
        const float4 q0 = cp[k];
        const float4 q1 = cp[k +     TILE];
        const float4 q2 = cp[k + 2 * TILE];
        const float4 q3 = cp[k + 3 * TILE];
        const float4 q4 = cp[k + 4 * TILE];
        const float w0 = s_w[(unsigned)(k)            / 20u];
        const float w1 = s_w[(unsigned)(k +     TILE) / 20u];
        const float w2 = s_w[(unsigned)(k + 2 * TILE) / 20u];
        const float w3 = s_w[(unsigned)(k + 3 * TILE) / 20u];
        const float w4 = s_w[(unsigned)(k + 4 * TILE) / 20u];
        focal_quad(q0, w0, accA, accB);
        focal_quad(q1, w1, accA, accB);
        focal_quad(q2, w2, accA, accB);
        focal_quad(q3, w3, accA, accB);
        focal_quad(q4, w4, accA, accB);
    }
    for (; k < nquad; k += TILE) {
        const float4 q = cp[k];
        const float wq = s_w[(unsigned)k / 20u];
        focal_quad(q, wq, accA, accB);
    }
    cls_part = accA + accB;

    // Block reduction: wave shuffle then cross-wave via LDS.
    for (int off = 32; off > 0; off >>= 1) {
        cls_part  += __shfl_down(cls_part,  off, 64);
        reg_part  += __shfl_down(reg_part,  off, 64);
        npos_part += __shfl_down(npos_part, off, 64);
    }
    const int wave = t >> 6;
    const int lane = t & 63;
    if (lane == 0) {
        s_red[0][wave] = cls_part;
        s_red[1][wave] = reg_part;
        s_red[2][wave] = npos_part;
    }
    __syncthreads();
    if (t == 0) {
        float cs = 0.0f, rs = 0.0f, ns = 0.0f;
        #pragma unroll
        for (int wv = 0; wv < 4; ++wv) {
            cs += s_red[0][wv];
            rs += s_red[1][wv];
            ns += s_red[2][wv];
        }
        // CONTENTION-FREE: plain stores to this block's private slot.
        float* slot = ws + ((size_t)(b * NTILES + tile) << 2);
        slot[0] = cs;
        slot[1] = rs;
        slot[2] = ns;
    }
}

// Merged reduce+finalize: one block, 8 waves; wave w reduces image w's 192
// slots (3 slots/lane), then thread 0 combines the 8 images.
__global__ __launch_bounds__(512) void tail_kernel(
    const float* __restrict__ ws_in,
    const float* __restrict__ ann,
    float* __restrict__ out)
{
    const int t    = threadIdx.x;
    const int b    = t >> 6;        // wave index == image
    const int lane = t & 63;

    float c = 0.0f, r = 0.0f, n = 0.0f;
    #pragma unroll
    for (int s = 0; s < 3; ++s) {
        const int tile = lane * 3 + s;   // 64*3 = 192 slots
        const float* slot = ws_in + ((size_t)(b * NTILES + tile) << 2);
        c += slot[0];
        r += slot[1];
        n += slot[2];
    }
    for (int off = 32; off > 0; off >>= 1) {
        c += __shfl_down(c, off, 64);
        r += __shfl_down(r, off, 64);
        n += __shfl_down(n, off, 64);
    }

    __shared__ float s_cls[B], s_reg[B];
    if (lane == 0) {
        bool has_valid = false;
        for (int m = 0; m < M; ++m)
            has_valid = has_valid || (ann[b * M * 5 + m * 5 + 4] != -1.0f);
        // cls accumulator is in log2 units -> scale by ln(2)
        const float cs = 0.69314718056f * c / fmaxf(n, 1.0f);
        s_cls[b] = has_valid ? cs : 0.0f;
        s_reg[b] = (n > 0.0f) ? (r / fmaxf(n * 4.0f, 1.0f)) : 0.0f;
    }
    __syncthreads();
    if (t == 0) {
        float cv = 0.0f, rv = 0.0f;
        #pragma unroll
        for (int i = 0; i < B; ++i) { cv += s_cls[i]; rv += s_reg[i]; }
        out[0] = cv * (1.0f / (float)B);
        out[1] = rv * (1.0f / (float)B);
    }
}

extern "C" void kernel_launch(void* const* d_in, const int* in_sizes, int n_in,
                              void* d_out, int out_size, void* d_ws, size_t ws_size,
                              hipStream_t stream) {
    const float* cls     = (const float*)d_in[0];
    const float* reg     = (const float*)d_in[1];
    const float* anchors = (const float*)d_in[2];
    const float* ann     = (const float*)d_in[3];
    float* out = (float*)d_out;
    float* ws  = (float*)d_ws;

    // No init kernel: every ws slot used is unconditionally overwritten
    // (plain stores), so the 0xAA poison never survives into a read.
    focal_main_kernel<<<dim3(NTILES, B), TILE, 0, stream>>>(cls, reg, anchors, ann, ws);
    tail_kernel<<<1, 512, 0, stream>>>(ws, ann, out);
}